// Round 1
// baseline (552.814 us; speedup 1.0000x reference)
//
#include <hip/hip_runtime.h>

// ---------------------------------------------------------------------------
// GCN: out = A_norm * relu(A_norm * X * W1 + b1) * W2 + b2
// A_norm = D^-1/2 (A + I) D^-1/2, built from 1.6M random edges + self loops.
//
// Pipeline:
//   k_init    : zero counters, detect int32-vs-int64 edge storage
//   k_count   : deg counts via int atomics
//   k_dis     : dis[i] = rsqrt(deg+1)
//   k_scan    : exclusive prefix sum -> CSR row_start (single block)
//   k_scatter : build csr_src / csr_norm
//   k_agg     : agg[i] = sum_e norm_e * x[src_e]  (128-dim, wave per node)
//   k_mm      : s[i] = relu(agg[i] @ W1 + b1) @ W2   (register-tiled fp32)
//   k_out     : out[i] = sum_e norm_e * s[src_e] + dis_i^2*s[i] + b2
// ---------------------------------------------------------------------------

__global__ void k_init(const int* __restrict__ edges, int* __restrict__ flag,
                       int* __restrict__ cnt, int* __restrict__ cursor, int n) {
    int i = blockIdx.x * blockDim.x + threadIdx.x;
    if (i < n) { cnt[i] = 0; cursor[i] = 0; }
    if (blockIdx.x == 0 && threadIdx.x < 64) {
        // If edges are int64 little-endian, odd 32-bit words are all zero
        // (values in [0, 50000)). If int32, they are random indices.
        int v = edges[2 * threadIdx.x + 1];
        unsigned long long b = __ballot(v != 0);
        if (threadIdx.x == 0) flag[0] = b ? 1 : 2;   // stride in int32 words
    }
}

__global__ void k_count(const int* __restrict__ edges, const int* __restrict__ flag,
                        int* __restrict__ cnt, long long E) {
    long long e = (long long)blockIdx.x * blockDim.x + threadIdx.x;
    if (e >= E) return;
    int stride = flag[0];
    int d = edges[(E + e) * stride];
    atomicAdd(&cnt[d], 1);
}

__global__ void k_dis(const int* __restrict__ cnt, float* __restrict__ dis, int n) {
    int i = blockIdx.x * blockDim.x + threadIdx.x;
    if (i < n) dis[i] = rsqrtf((float)cnt[i] + 1.0f);   // +1 = self loop
}

__global__ void k_scan(const int* __restrict__ cnt, int* __restrict__ row_start, int n) {
    __shared__ int sums[1024];
    int t = threadIdx.x;
    int C = (n + 1023) / 1024;
    int lo = t * C;
    int hi = lo + C; if (hi > n) hi = n;
    if (lo > n) lo = n;
    int local = 0;
    for (int i = lo; i < hi; ++i) local += cnt[i];
    sums[t] = local;
    __syncthreads();
    int val = local;
    for (int off = 1; off < 1024; off <<= 1) {
        int other = (t >= off) ? sums[t - off] : 0;
        __syncthreads();
        val += other;
        sums[t] = val;
        __syncthreads();
    }
    int run = val - local;   // exclusive prefix
    for (int i = lo; i < hi; ++i) { row_start[i] = run; run += cnt[i]; }
    if (hi == n) row_start[n] = run;
}

__global__ void k_scatter(const int* __restrict__ edges, const int* __restrict__ flag,
                          const int* __restrict__ row_start, int* __restrict__ cursor,
                          const float* __restrict__ dis, int* __restrict__ csr_src,
                          float* __restrict__ csr_norm, long long E) {
    long long e = (long long)blockIdx.x * blockDim.x + threadIdx.x;
    if (e >= E) return;
    int stride = flag[0];
    int s = edges[e * stride];
    int d = edges[(E + e) * stride];
    int pos = atomicAdd(&cursor[d], 1);
    int j = row_start[d] + pos;
    csr_src[j] = s;
    csr_norm[j] = dis[s] * dis[d];
}

// One wave (64 lanes) per node; each lane owns features {lane, lane+64}.
__global__ __launch_bounds__(256) void k_agg(
        const float* __restrict__ x, const int* __restrict__ csr_src,
        const float* __restrict__ csr_norm, const int* __restrict__ row_start,
        const float* __restrict__ dis, float* __restrict__ agg, int n) {
    int wid  = (blockIdx.x * blockDim.x + threadIdx.x) >> 6;
    int lane = threadIdx.x & 63;
    if (wid >= n) return;
    int start = row_start[wid], end = row_start[wid + 1];
    float dn = dis[wid];
    float nself = dn * dn;
    const float* xi = x + (size_t)wid * 128;
    float acc0 = nself * xi[lane];
    float acc1 = nself * xi[lane + 64];
    int e = start;
    for (; e + 1 < end; e += 2) {
        int s0 = csr_src[e], s1 = csr_src[e + 1];
        float n0 = csr_norm[e], n1 = csr_norm[e + 1];
        const float* p0 = x + (size_t)s0 * 128;
        const float* p1 = x + (size_t)s1 * 128;
        float a0 = p0[lane], b0 = p0[lane + 64];
        float a1 = p1[lane], b1v = p1[lane + 64];
        acc0 += n0 * a0;  acc1 += n0 * b0;
        acc0 += n1 * a1;  acc1 += n1 * b1v;
    }
    if (e < end) {
        int s0 = csr_src[e];
        float n0 = csr_norm[e];
        const float* p0 = x + (size_t)s0 * 128;
        acc0 += n0 * p0[lane];
        acc1 += n0 * p0[lane + 64];
    }
    agg[(size_t)wid * 128 + lane]      = acc0;
    agg[(size_t)wid * 128 + lane + 64] = acc1;
}

// s[i] = relu(agg[i] @ W1 + b1) @ W2.  Thread = 8 cols x 4 nodes.
// Block 256 threads = 32 col-groups x 8 node-groups -> 32 nodes/block.
__global__ __launch_bounds__(256) void k_mm(
        const float* __restrict__ agg, const float* __restrict__ W1,
        const float* __restrict__ b1, const float* __restrict__ W2,
        float* __restrict__ sv, int n) {
    int cg = threadIdx.x & 31;        // col group: cols cg*8 .. +7
    int nl = threadIdx.x >> 5;        // node group 0..7 (4 nodes each)
    int node0 = blockIdx.x * 32 + nl * 4;
    int c0 = cg * 8;

    const float* vb[4];
#pragma unroll
    for (int j = 0; j < 4; ++j) {
        int nj = node0 + j; if (nj > n - 1) nj = n - 1;
        vb[j] = agg + (size_t)nj * 128;
    }

    float acc[4][8];
#pragma unroll
    for (int j = 0; j < 4; ++j)
#pragma unroll
        for (int c = 0; c < 8; ++c) acc[j][c] = 0.f;

    for (int k = 0; k < 128; k += 4) {
        float vvf[4][4];
#pragma unroll
        for (int j = 0; j < 4; ++j) {
            float4 q = *(const float4*)(vb[j] + k);
            vvf[j][0] = q.x; vvf[j][1] = q.y; vvf[j][2] = q.z; vvf[j][3] = q.w;
        }
        float wf[4][8];
        const float* wr = W1 + (size_t)k * 256 + c0;
#pragma unroll
        for (int kk = 0; kk < 4; ++kk) {
            float4 wa = *(const float4*)(wr + kk * 256);
            float4 wb = *(const float4*)(wr + kk * 256 + 4);
            wf[kk][0] = wa.x; wf[kk][1] = wa.y; wf[kk][2] = wa.z; wf[kk][3] = wa.w;
            wf[kk][4] = wb.x; wf[kk][5] = wb.y; wf[kk][6] = wb.z; wf[kk][7] = wb.w;
        }
#pragma unroll
        for (int j = 0; j < 4; ++j)
#pragma unroll
            for (int kk = 0; kk < 4; ++kk)
#pragma unroll
                for (int c = 0; c < 8; ++c)
                    acc[j][c] += vvf[j][kk] * wf[kk][c];
    }

    // epilogue: relu + dot with W2 slice
    float p[4] = {0.f, 0.f, 0.f, 0.f};
#pragma unroll
    for (int c = 0; c < 8; ++c) {
        float bb = b1[c0 + c];
        float w2 = W2[c0 + c];
#pragma unroll
        for (int j = 0; j < 4; ++j) {
            float t = acc[j][c] + bb;
            t = t > 0.f ? t : 0.f;
            p[j] += t * w2;
        }
    }
    // reduce across the 32 col-group lanes
#pragma unroll
    for (int j = 0; j < 4; ++j) {
        float v = p[j];
        for (int off = 16; off; off >>= 1) v += __shfl_xor(v, off, 32);
        if (cg == 0 && node0 + j < n) sv[node0 + j] = v;
    }
}

// out[i] = b2 + dis_i^2 * s[i] + sum_e norm_e * s[src_e]; wave per node.
__global__ __launch_bounds__(256) void k_out(
        const float* __restrict__ sv, const int* __restrict__ csr_src,
        const float* __restrict__ csr_norm, const int* __restrict__ row_start,
        const float* __restrict__ dis, const float* __restrict__ b2,
        float* __restrict__ out, int n) {
    int wid  = (blockIdx.x * blockDim.x + threadIdx.x) >> 6;
    int lane = threadIdx.x & 63;
    if (wid >= n) return;
    int start = row_start[wid], end = row_start[wid + 1];
    float acc = 0.f;
    for (int e = start + lane; e < end; e += 64)
        acc += csr_norm[e] * sv[csr_src[e]];
    for (int off = 32; off; off >>= 1) acc += __shfl_down(acc, off, 64);
    if (lane == 0) {
        float dn = dis[wid];
        out[wid] = acc + dn * dn * sv[wid] + b2[0];
    }
}

extern "C" void kernel_launch(void* const* d_in, const int* in_sizes, int n_in,
                              void* d_out, int out_size, void* d_ws, size_t ws_size,
                              hipStream_t stream) {
    const float* x  = (const float*)d_in[0];
    const int*   ei = (const int*)d_in[1];
    const float* W1 = (const float*)d_in[2];
    const float* b1 = (const float*)d_in[3];
    const float* W2 = (const float*)d_in[4];
    const float* b2 = (const float*)d_in[5];
    float* out = (float*)d_out;

    const int N = in_sizes[0] / 128;
    const long long E = in_sizes[1] / 2;

    char* ws = (char*)d_ws;
    size_t off = 0;
    auto take = [&](size_t bytes) -> char* {
        char* p = ws + off;
        off = (off + bytes + 255) & ~(size_t)255;
        return p;
    };
    int*   flag     = (int*)take(4);
    int*   cnt      = (int*)take((size_t)N * 4);
    int*   cursor   = (int*)take((size_t)N * 4);
    int*   rs       = (int*)take((size_t)(N + 1) * 4);
    float* dis      = (float*)take((size_t)N * 4);
    float* sv       = (float*)take((size_t)N * 4);
    int*   csr_src  = (int*)take((size_t)E * 4);
    float* csr_norm = (float*)take((size_t)E * 4);
    float* agg      = (float*)take((size_t)N * 128 * 4);

    int nb_n = (N + 255) / 256;
    int nb_e = (int)((E + 255) / 256);

    k_init   <<<nb_n, 256, 0, stream>>>(ei, flag, cnt, cursor, N);
    k_count  <<<nb_e, 256, 0, stream>>>(ei, flag, cnt, E);
    k_dis    <<<nb_n, 256, 0, stream>>>(cnt, dis, N);
    k_scan   <<<1, 1024, 0, stream>>>(cnt, rs, N);
    k_scatter<<<nb_e, 256, 0, stream>>>(ei, flag, rs, cursor, dis, csr_src, csr_norm, E);
    k_agg    <<<(N + 3) / 4, 256, 0, stream>>>(x, csr_src, csr_norm, rs, dis, agg, N);
    k_mm     <<<(N + 31) / 32, 256, 0, stream>>>(agg, W1, b1, W2, sv, N);
    k_out    <<<(N + 3) / 4, 256, 0, stream>>>(sv, csr_src, csr_norm, rs, dis, b2, out, N);
}

// Round 2
// 482.074 us; speedup vs baseline: 1.1467x; 1.1467x over previous
//
#include <hip/hip_runtime.h>

// ---------------------------------------------------------------------------
// GCN: out = A_norm * relu(A_norm * X * W1 + b1) * W2 + b2
// A_norm = D^-1/2 (A + I) D^-1/2, built from 1.6M random edges + self loops.
//
// Round-2 changes (vs round 1):
//  * k_count now assigns each edge its within-destination rank pos[e] via the
//    SAME atomic it already did for the histogram -> k_scatter has no atomic
//    and no store->atomic dependency.
//  * csr_norm dropped entirely: norm = dis[src]*dis[dst] recomputed on the fly
//    (dis is 200 KB, L2-resident). Scattered stores per edge: 2 -> 1.
//  * k_dis fused into k_scan epilogue (one fewer launch).
//  * k_agg: float2 loads (512B/wave/edge in one instr) + 4-edge unroll.
// ---------------------------------------------------------------------------

__global__ void k_init(const int* __restrict__ edges, int* __restrict__ flag,
                       int* __restrict__ cnt, int n) {
    int i = blockIdx.x * blockDim.x + threadIdx.x;
    if (i < n) cnt[i] = 0;
    if (blockIdx.x == 0 && threadIdx.x < 64) {
        // If edges are int64 little-endian, odd 32-bit words are all zero
        // (values in [0, 50000)). If int32, they are random indices.
        int v = edges[2 * threadIdx.x + 1];
        unsigned long long b = __ballot(v != 0);
        if (threadIdx.x == 0) flag[0] = b ? 1 : 2;   // stride in int32 words
    }
}

// Histogram + rank assignment: pos[e] = #earlier-processed edges with same dst.
__global__ void k_count(const int* __restrict__ edges, const int* __restrict__ flag,
                        int* __restrict__ cnt, int* __restrict__ pos, long long E) {
    long long e = (long long)blockIdx.x * blockDim.x + threadIdx.x;
    if (e >= E) return;
    int stride = flag[0];
    int d = edges[(E + e) * stride];
    pos[e] = atomicAdd(&cnt[d], 1);
}

// Exclusive prefix sum over cnt -> row_start, plus dis = rsqrt(deg+1).
__global__ void k_scan(const int* __restrict__ cnt, int* __restrict__ row_start,
                       float* __restrict__ dis, int n) {
    __shared__ int sums[1024];
    int t = threadIdx.x;
    int C = (n + 1023) / 1024;
    int lo = t * C;
    int hi = lo + C; if (hi > n) hi = n;
    if (lo > n) lo = n;
    int local = 0;
    for (int i = lo; i < hi; ++i) local += cnt[i];
    sums[t] = local;
    __syncthreads();
    int val = local;
    for (int off = 1; off < 1024; off <<= 1) {
        int other = (t >= off) ? sums[t - off] : 0;
        __syncthreads();
        val += other;
        sums[t] = val;
        __syncthreads();
    }
    int run = val - local;   // exclusive prefix
    for (int i = lo; i < hi; ++i) {
        row_start[i] = run;
        run += cnt[i];
        dis[i] = rsqrtf((float)cnt[i] + 1.0f);   // +1 = self loop
    }
    if (hi == n) row_start[n] = run;
}

// Pure scattered store: csr_src[rs[dst] + pos[e]] = src. No atomics.
__global__ void k_scatter(const int* __restrict__ edges, const int* __restrict__ flag,
                          const int* __restrict__ row_start, const int* __restrict__ pos,
                          int* __restrict__ csr_src, long long E) {
    long long e = (long long)blockIdx.x * blockDim.x + threadIdx.x;
    if (e >= E) return;
    int stride = flag[0];
    int s = edges[e * stride];
    int d = edges[(E + e) * stride];
    csr_src[row_start[d] + pos[e]] = s;
}

// One wave (64 lanes) per node; lane owns features {2*lane, 2*lane+1}.
// norm recomputed on the fly from dis (L2-resident).
__global__ __launch_bounds__(256) void k_agg(
        const float* __restrict__ x, const int* __restrict__ csr_src,
        const int* __restrict__ row_start, const float* __restrict__ dis,
        float* __restrict__ agg, int n) {
    int wid  = (blockIdx.x * blockDim.x + threadIdx.x) >> 6;
    int lane = threadIdx.x & 63;
    if (wid >= n) return;
    int start = row_start[wid], end = row_start[wid + 1];
    float dn = dis[wid];
    const float2* xi = (const float2*)(x + (size_t)wid * 128);
    float2 self = xi[lane];
    float acc0 = dn * dn * self.x;
    float acc1 = dn * dn * self.y;
    int e = start;
    for (; e + 3 < end; e += 4) {
        int s0 = csr_src[e],     s1 = csr_src[e + 1];
        int s2 = csr_src[e + 2], s3 = csr_src[e + 3];
        float n0 = dis[s0] * dn, n1 = dis[s1] * dn;
        float n2 = dis[s2] * dn, n3 = dis[s3] * dn;
        float2 v0 = ((const float2*)(x + (size_t)s0 * 128))[lane];
        float2 v1 = ((const float2*)(x + (size_t)s1 * 128))[lane];
        float2 v2 = ((const float2*)(x + (size_t)s2 * 128))[lane];
        float2 v3 = ((const float2*)(x + (size_t)s3 * 128))[lane];
        acc0 += n0 * v0.x; acc1 += n0 * v0.y;
        acc0 += n1 * v1.x; acc1 += n1 * v1.y;
        acc0 += n2 * v2.x; acc1 += n2 * v2.y;
        acc0 += n3 * v3.x; acc1 += n3 * v3.y;
    }
    for (; e < end; ++e) {
        int s0 = csr_src[e];
        float n0 = dis[s0] * dn;
        float2 v0 = ((const float2*)(x + (size_t)s0 * 128))[lane];
        acc0 += n0 * v0.x; acc1 += n0 * v0.y;
    }
    ((float2*)(agg + (size_t)wid * 128))[lane] = make_float2(acc0, acc1);
}

// s[i] = relu(agg[i] @ W1 + b1) @ W2.  Thread = 8 cols x 4 nodes.
// Block 256 threads = 32 col-groups x 8 node-groups -> 32 nodes/block.
__global__ __launch_bounds__(256) void k_mm(
        const float* __restrict__ agg, const float* __restrict__ W1,
        const float* __restrict__ b1, const float* __restrict__ W2,
        float* __restrict__ sv, int n) {
    int cg = threadIdx.x & 31;        // col group: cols cg*8 .. +7
    int nl = threadIdx.x >> 5;        // node group 0..7 (4 nodes each)
    int node0 = blockIdx.x * 32 + nl * 4;
    int c0 = cg * 8;

    const float* vb[4];
#pragma unroll
    for (int j = 0; j < 4; ++j) {
        int nj = node0 + j; if (nj > n - 1) nj = n - 1;
        vb[j] = agg + (size_t)nj * 128;
    }

    float acc[4][8];
#pragma unroll
    for (int j = 0; j < 4; ++j)
#pragma unroll
        for (int c = 0; c < 8; ++c) acc[j][c] = 0.f;

    for (int k = 0; k < 128; k += 4) {
        float vvf[4][4];
#pragma unroll
        for (int j = 0; j < 4; ++j) {
            float4 q = *(const float4*)(vb[j] + k);
            vvf[j][0] = q.x; vvf[j][1] = q.y; vvf[j][2] = q.z; vvf[j][3] = q.w;
        }
        float wf[4][8];
        const float* wr = W1 + (size_t)k * 256 + c0;
#pragma unroll
        for (int kk = 0; kk < 4; ++kk) {
            float4 wa = *(const float4*)(wr + kk * 256);
            float4 wb = *(const float4*)(wr + kk * 256 + 4);
            wf[kk][0] = wa.x; wf[kk][1] = wa.y; wf[kk][2] = wa.z; wf[kk][3] = wa.w;
            wf[kk][4] = wb.x; wf[kk][5] = wb.y; wf[kk][6] = wb.z; wf[kk][7] = wb.w;
        }
#pragma unroll
        for (int j = 0; j < 4; ++j)
#pragma unroll
            for (int kk = 0; kk < 4; ++kk)
#pragma unroll
                for (int c = 0; c < 8; ++c)
                    acc[j][c] += vvf[j][kk] * wf[kk][c];
    }

    // epilogue: relu + dot with W2 slice
    float p[4] = {0.f, 0.f, 0.f, 0.f};
#pragma unroll
    for (int c = 0; c < 8; ++c) {
        float bb = b1[c0 + c];
        float w2 = W2[c0 + c];
#pragma unroll
        for (int j = 0; j < 4; ++j) {
            float t = acc[j][c] + bb;
            t = t > 0.f ? t : 0.f;
            p[j] += t * w2;
        }
    }
    // reduce across the 32 col-group lanes
#pragma unroll
    for (int j = 0; j < 4; ++j) {
        float v = p[j];
        for (int off = 16; off; off >>= 1) v += __shfl_xor(v, off, 32);
        if (cg == 0 && node0 + j < n) sv[node0 + j] = v;
    }
}

// out[i] = b2 + dis_i^2 * s[i] + sum_e dis[src]*dis[i] * s[src]; wave per node.
__global__ __launch_bounds__(256) void k_out(
        const float* __restrict__ sv, const int* __restrict__ csr_src,
        const int* __restrict__ row_start, const float* __restrict__ dis,
        const float* __restrict__ b2, float* __restrict__ out, int n) {
    int wid  = (blockIdx.x * blockDim.x + threadIdx.x) >> 6;
    int lane = threadIdx.x & 63;
    if (wid >= n) return;
    int start = row_start[wid], end = row_start[wid + 1];
    float dn = dis[wid];
    float acc = 0.f;
    for (int e = start + lane; e < end; e += 64) {
        int s = csr_src[e];
        acc += dis[s] * sv[s];
    }
    for (int off = 32; off; off >>= 1) acc += __shfl_down(acc, off, 64);
    if (lane == 0)
        out[wid] = dn * (acc + dn * sv[wid]) + b2[0];
}

extern "C" void kernel_launch(void* const* d_in, const int* in_sizes, int n_in,
                              void* d_out, int out_size, void* d_ws, size_t ws_size,
                              hipStream_t stream) {
    const float* x  = (const float*)d_in[0];
    const int*   ei = (const int*)d_in[1];
    const float* W1 = (const float*)d_in[2];
    const float* b1 = (const float*)d_in[3];
    const float* W2 = (const float*)d_in[4];
    const float* b2 = (const float*)d_in[5];
    float* out = (float*)d_out;

    const int N = in_sizes[0] / 128;
    const long long E = in_sizes[1] / 2;

    char* ws = (char*)d_ws;
    size_t off = 0;
    auto take = [&](size_t bytes) -> char* {
        char* p = ws + off;
        off = (off + bytes + 255) & ~(size_t)255;
        return p;
    };
    int*   flag     = (int*)take(4);
    int*   cnt      = (int*)take((size_t)N * 4);
    int*   rs       = (int*)take((size_t)(N + 1) * 4);
    float* dis      = (float*)take((size_t)N * 4);
    float* sv       = (float*)take((size_t)N * 4);
    int*   pos      = (int*)take((size_t)E * 4);
    int*   csr_src  = (int*)take((size_t)E * 4);
    float* agg      = (float*)take((size_t)N * 128 * 4);

    int nb_n = (N + 255) / 256;
    int nb_e = (int)((E + 255) / 256);

    k_init   <<<nb_n, 256, 0, stream>>>(ei, flag, cnt, N);
    k_count  <<<nb_e, 256, 0, stream>>>(ei, flag, cnt, pos, E);
    k_scan   <<<1, 1024, 0, stream>>>(cnt, rs, dis, N);
    k_scatter<<<nb_e, 256, 0, stream>>>(ei, flag, rs, pos, csr_src, E);
    k_agg    <<<(N + 3) / 4, 256, 0, stream>>>(x, csr_src, rs, dis, agg, N);
    k_mm     <<<(N + 31) / 32, 256, 0, stream>>>(agg, W1, b1, W2, sv, N);
    k_out    <<<(N + 3) / 4, 256, 0, stream>>>(sv, csr_src, rs, dis, b2, out, N);
}

// Round 3
// 385.543 us; speedup vs baseline: 1.4339x; 1.2504x over previous
//
#include <hip/hip_runtime.h>

// ---------------------------------------------------------------------------
// GCN: out = A_norm * relu(A_norm * X * W1 + b1) * W2 + b2
// A_norm = D^-1/2 (A + I) D^-1/2, built from 1.6M random edges + self loops.
//
// Round-3 change: the 110us single-block k_scan is replaced by a 3-launch
// hierarchical scan (partial sums -> wave scan of 25 partials -> apply),
// each launch fully parallel / a few us.
// ---------------------------------------------------------------------------

#define SCAN_TILE 2048   // 256 threads x 8 elements

__global__ void k_init(const int* __restrict__ edges, int* __restrict__ flag,
                       int* __restrict__ cnt, int n) {
    int i = blockIdx.x * blockDim.x + threadIdx.x;
    if (i < n) cnt[i] = 0;
    if (blockIdx.x == 0 && threadIdx.x < 64) {
        // If edges are int64 little-endian, odd 32-bit words are all zero
        // (values in [0, 50000)). If int32, they are random indices.
        int v = edges[2 * threadIdx.x + 1];
        unsigned long long b = __ballot(v != 0);
        if (threadIdx.x == 0) flag[0] = b ? 1 : 2;   // stride in int32 words
    }
}

// Histogram + rank assignment: pos[e] = #earlier-processed edges with same dst.
__global__ void k_count(const int* __restrict__ edges, const int* __restrict__ flag,
                        int* __restrict__ cnt, int* __restrict__ pos, long long E) {
    long long e = (long long)blockIdx.x * blockDim.x + threadIdx.x;
    if (e >= E) return;
    int stride = flag[0];
    int d = edges[(E + e) * stride];
    pos[e] = atomicAdd(&cnt[d], 1);
}

// Per-block sums of cnt (8 elems/thread).
__global__ __launch_bounds__(256) void k_scan_partial(
        const int* __restrict__ cnt, int* __restrict__ bsum, int n) {
    int t = threadIdx.x;
    int idx = blockIdx.x * SCAN_TILE + t * 8;
    int s = 0;
#pragma unroll
    for (int j = 0; j < 8; ++j) {
        int i = idx + j;
        if (i < n) s += cnt[i];
    }
    for (int off = 32; off; off >>= 1) s += __shfl_down(s, off, 64);
    __shared__ int ws[4];
    if ((t & 63) == 0) ws[t >> 6] = s;
    __syncthreads();
    if (t == 0) bsum[blockIdx.x] = ws[0] + ws[1] + ws[2] + ws[3];
}

// Exclusive scan of <=64 block sums, in place, one wave.
__global__ void k_scan_tops(int* __restrict__ bsum, int nb) {
    int t = threadIdx.x;
    int w = (t < nb) ? bsum[t] : 0;
    int v = w;
    for (int off = 1; off < 64; off <<= 1) {
        int u = __shfl_up(v, off, 64);
        if (t >= off) v += u;
    }
    if (t < nb) bsum[t] = v - w;   // exclusive
}

// Apply: recompute intra-block prefix, add block offset, emit row_start & dis.
__global__ __launch_bounds__(256) void k_scan_apply(
        const int* __restrict__ cnt, const int* __restrict__ bsum,
        int* __restrict__ row_start, float* __restrict__ dis, int n) {
    int t = threadIdx.x;
    int lane = t & 63, w = t >> 6;
    int idx = blockIdx.x * SCAN_TILE + t * 8;
    int vals[8];
    int s = 0;
#pragma unroll
    for (int j = 0; j < 8; ++j) {
        int i = idx + j;
        vals[j] = (i < n) ? cnt[i] : 0;
        s += vals[j];
    }
    int inc = s;
    for (int off = 1; off < 64; off <<= 1) {
        int u = __shfl_up(inc, off, 64);
        if (lane >= off) inc += u;
    }
    __shared__ int wsum[4];
    if (lane == 63) wsum[w] = inc;
    __syncthreads();
    int woff = 0;
    for (int i = 0; i < w; ++i) woff += wsum[i];
    int ex = bsum[blockIdx.x] + woff + inc - s;  // exclusive prefix of this chunk
#pragma unroll
    for (int j = 0; j < 8; ++j) {
        int i = idx + j;
        if (i < n) {
            row_start[i] = ex;
            dis[i] = rsqrtf((float)vals[j] + 1.0f);  // +1 = self loop
            ex += vals[j];
        }
    }
    if (idx <= n && n < idx + 8) row_start[n] = ex;  // unique thread
}

// Pure scattered store: csr_src[rs[dst] + pos[e]] = src. No atomics.
__global__ void k_scatter(const int* __restrict__ edges, const int* __restrict__ flag,
                          const int* __restrict__ row_start, const int* __restrict__ pos,
                          int* __restrict__ csr_src, long long E) {
    long long e = (long long)blockIdx.x * blockDim.x + threadIdx.x;
    if (e >= E) return;
    int stride = flag[0];
    int s = edges[e * stride];
    int d = edges[(E + e) * stride];
    csr_src[row_start[d] + pos[e]] = s;
}

// One wave (64 lanes) per node; lane owns features {2*lane, 2*lane+1}.
// norm recomputed on the fly from dis (L2-resident).
__global__ __launch_bounds__(256) void k_agg(
        const float* __restrict__ x, const int* __restrict__ csr_src,
        const int* __restrict__ row_start, const float* __restrict__ dis,
        float* __restrict__ agg, int n) {
    int wid  = (blockIdx.x * blockDim.x + threadIdx.x) >> 6;
    int lane = threadIdx.x & 63;
    if (wid >= n) return;
    int start = row_start[wid], end = row_start[wid + 1];
    float dn = dis[wid];
    const float2* xi = (const float2*)(x + (size_t)wid * 128);
    float2 self = xi[lane];
    float acc0 = dn * dn * self.x;
    float acc1 = dn * dn * self.y;
    int e = start;
    for (; e + 3 < end; e += 4) {
        int s0 = csr_src[e],     s1 = csr_src[e + 1];
        int s2 = csr_src[e + 2], s3 = csr_src[e + 3];
        float n0 = dis[s0] * dn, n1 = dis[s1] * dn;
        float n2 = dis[s2] * dn, n3 = dis[s3] * dn;
        float2 v0 = ((const float2*)(x + (size_t)s0 * 128))[lane];
        float2 v1 = ((const float2*)(x + (size_t)s1 * 128))[lane];
        float2 v2 = ((const float2*)(x + (size_t)s2 * 128))[lane];
        float2 v3 = ((const float2*)(x + (size_t)s3 * 128))[lane];
        acc0 += n0 * v0.x; acc1 += n0 * v0.y;
        acc0 += n1 * v1.x; acc1 += n1 * v1.y;
        acc0 += n2 * v2.x; acc1 += n2 * v2.y;
        acc0 += n3 * v3.x; acc1 += n3 * v3.y;
    }
    for (; e < end; ++e) {
        int s0 = csr_src[e];
        float n0 = dis[s0] * dn;
        float2 v0 = ((const float2*)(x + (size_t)s0 * 128))[lane];
        acc0 += n0 * v0.x; acc1 += n0 * v0.y;
    }
    ((float2*)(agg + (size_t)wid * 128))[lane] = make_float2(acc0, acc1);
}

// s[i] = relu(agg[i] @ W1 + b1) @ W2.  Thread = 8 cols x 4 nodes.
// Block 256 threads = 32 col-groups x 8 node-groups -> 32 nodes/block.
__global__ __launch_bounds__(256) void k_mm(
        const float* __restrict__ agg, const float* __restrict__ W1,
        const float* __restrict__ b1, const float* __restrict__ W2,
        float* __restrict__ sv, int n) {
    int cg = threadIdx.x & 31;        // col group: cols cg*8 .. +7
    int nl = threadIdx.x >> 5;        // node group 0..7 (4 nodes each)
    int node0 = blockIdx.x * 32 + nl * 4;
    int c0 = cg * 8;

    const float* vb[4];
#pragma unroll
    for (int j = 0; j < 4; ++j) {
        int nj = node0 + j; if (nj > n - 1) nj = n - 1;
        vb[j] = agg + (size_t)nj * 128;
    }

    float acc[4][8];
#pragma unroll
    for (int j = 0; j < 4; ++j)
#pragma unroll
        for (int c = 0; c < 8; ++c) acc[j][c] = 0.f;

    for (int k = 0; k < 128; k += 4) {
        float vvf[4][4];
#pragma unroll
        for (int j = 0; j < 4; ++j) {
            float4 q = *(const float4*)(vb[j] + k);
            vvf[j][0] = q.x; vvf[j][1] = q.y; vvf[j][2] = q.z; vvf[j][3] = q.w;
        }
        float wf[4][8];
        const float* wr = W1 + (size_t)k * 256 + c0;
#pragma unroll
        for (int kk = 0; kk < 4; ++kk) {
            float4 wa = *(const float4*)(wr + kk * 256);
            float4 wb = *(const float4*)(wr + kk * 256 + 4);
            wf[kk][0] = wa.x; wf[kk][1] = wa.y; wf[kk][2] = wa.z; wf[kk][3] = wa.w;
            wf[kk][4] = wb.x; wf[kk][5] = wb.y; wf[kk][6] = wb.z; wf[kk][7] = wb.w;
        }
#pragma unroll
        for (int j = 0; j < 4; ++j)
#pragma unroll
            for (int kk = 0; kk < 4; ++kk)
#pragma unroll
                for (int c = 0; c < 8; ++c)
                    acc[j][c] += vvf[j][kk] * wf[kk][c];
    }

    // epilogue: relu + dot with W2 slice
    float p[4] = {0.f, 0.f, 0.f, 0.f};
#pragma unroll
    for (int c = 0; c < 8; ++c) {
        float bb = b1[c0 + c];
        float w2 = W2[c0 + c];
#pragma unroll
        for (int j = 0; j < 4; ++j) {
            float t = acc[j][c] + bb;
            t = t > 0.f ? t : 0.f;
            p[j] += t * w2;
        }
    }
    // reduce across the 32 col-group lanes
#pragma unroll
    for (int j = 0; j < 4; ++j) {
        float v = p[j];
        for (int off = 16; off; off >>= 1) v += __shfl_xor(v, off, 32);
        if (cg == 0 && node0 + j < n) sv[node0 + j] = v;
    }
}

// out[i] = b2 + dis_i^2 * s[i] + sum_e dis[src]*dis[i] * s[src]; wave per node.
__global__ __launch_bounds__(256) void k_out(
        const float* __restrict__ sv, const int* __restrict__ csr_src,
        const int* __restrict__ row_start, const float* __restrict__ dis,
        const float* __restrict__ b2, float* __restrict__ out, int n) {
    int wid  = (blockIdx.x * blockDim.x + threadIdx.x) >> 6;
    int lane = threadIdx.x & 63;
    if (wid >= n) return;
    int start = row_start[wid], end = row_start[wid + 1];
    float dn = dis[wid];
    float acc = 0.f;
    for (int e = start + lane; e < end; e += 64) {
        int s = csr_src[e];
        acc += dis[s] * sv[s];
    }
    for (int off = 32; off; off >>= 1) acc += __shfl_down(acc, off, 64);
    if (lane == 0)
        out[wid] = dn * (acc + dn * sv[wid]) + b2[0];
}

extern "C" void kernel_launch(void* const* d_in, const int* in_sizes, int n_in,
                              void* d_out, int out_size, void* d_ws, size_t ws_size,
                              hipStream_t stream) {
    const float* x  = (const float*)d_in[0];
    const int*   ei = (const int*)d_in[1];
    const float* W1 = (const float*)d_in[2];
    const float* b1 = (const float*)d_in[3];
    const float* W2 = (const float*)d_in[4];
    const float* b2 = (const float*)d_in[5];
    float* out = (float*)d_out;

    const int N = in_sizes[0] / 128;
    const long long E = in_sizes[1] / 2;

    char* ws = (char*)d_ws;
    size_t off = 0;
    auto take = [&](size_t bytes) -> char* {
        char* p = ws + off;
        off = (off + bytes + 255) & ~(size_t)255;
        return p;
    };
    int*   flag     = (int*)take(4);
    int*   cnt      = (int*)take((size_t)N * 4);
    int*   rs       = (int*)take((size_t)(N + 1) * 4);
    float* dis      = (float*)take((size_t)N * 4);
    float* sv       = (float*)take((size_t)N * 4);
    int*   bsum     = (int*)take(64 * 4);
    int*   pos      = (int*)take((size_t)E * 4);
    int*   csr_src  = (int*)take((size_t)E * 4);
    float* agg      = (float*)take((size_t)N * 128 * 4);

    int nb_n = (N + 255) / 256;
    int nb_e = (int)((E + 255) / 256);
    int nb_s = (N + SCAN_TILE - 1) / SCAN_TILE;   // 25 blocks for N=50000

    k_init        <<<nb_n, 256, 0, stream>>>(ei, flag, cnt, N);
    k_count       <<<nb_e, 256, 0, stream>>>(ei, flag, cnt, pos, E);
    k_scan_partial<<<nb_s, 256, 0, stream>>>(cnt, bsum, N);
    k_scan_tops   <<<1, 64, 0, stream>>>(bsum, nb_s);
    k_scan_apply  <<<nb_s, 256, 0, stream>>>(cnt, bsum, rs, dis, N);
    k_scatter     <<<nb_e, 256, 0, stream>>>(ei, flag, rs, pos, csr_src, E);
    k_agg         <<<(N + 3) / 4, 256, 0, stream>>>(x, csr_src, rs, dis, agg, N);
    k_mm          <<<(N + 31) / 32, 256, 0, stream>>>(agg, W1, b1, W2, sv, N);
    k_out         <<<(N + 3) / 4, 256, 0, stream>>>(sv, csr_src, rs, dis, b2, out, N);
}

// Round 4
// 300.258 us; speedup vs baseline: 1.8411x; 1.2840x over previous
//
#include <hip/hip_runtime.h>

// ---------------------------------------------------------------------------
// GCN: out = A_norm * relu(A_norm * X * W1 + b1) * W2 + b2
// A_norm = D^-1/2 (A + I) D^-1/2, built from 1.6M random edges + self loops.
//
// Round-4 changes:
//  * x cast once to bf16 (k_prep_x); k_agg gathers 256B bf16 rows instead of
//    512B fp32 rows -> halves the fabric traffic that bound it (360MB FETCH).
//  * agg stored bf16; W1 pre-transposed to bf16 (k_prep_w); k_mm now uses
//    v_mfma_f32_16x16x32_bf16 (A-frags straight from row-major agg, B-frags
//    from W1t, relu*W2 epilogue + 16-lane butterfly reduction).
// ---------------------------------------------------------------------------

#define SCAN_TILE 2048   // 256 threads x 8 elements

typedef __attribute__((ext_vector_type(8))) short bf16x8;
typedef __attribute__((ext_vector_type(4))) float f32x4;

__device__ inline unsigned short f2bf(float f) {
    unsigned int b = __float_as_uint(f);
    unsigned int r = b + 0x7FFFu + ((b >> 16) & 1u);   // round-to-nearest-even
    return (unsigned short)(r >> 16);
}
__device__ inline float bf_lo(unsigned int u) { return __uint_as_float(u << 16); }
__device__ inline float bf_hi(unsigned int u) { return __uint_as_float(u & 0xFFFF0000u); }

__global__ void k_init(const int* __restrict__ edges, int* __restrict__ flag,
                       int* __restrict__ cnt, int n) {
    int i = blockIdx.x * blockDim.x + threadIdx.x;
    if (i < n) cnt[i] = 0;
    if (blockIdx.x == 0 && threadIdx.x < 64) {
        // int64 edges little-endian -> odd 32-bit words all zero (vals < 50000)
        int v = edges[2 * threadIdx.x + 1];
        unsigned long long b = __ballot(v != 0);
        if (threadIdx.x == 0) flag[0] = b ? 1 : 2;   // stride in int32 words
    }
}

// x (fp32) -> xh (bf16), 4 elems/thread
__global__ __launch_bounds__(256) void k_prep_x(const float* __restrict__ x,
        unsigned short* __restrict__ xh, int total4) {
    int i = blockIdx.x * 256 + threadIdx.x;
    if (i >= total4) return;
    float4 v = *(const float4*)(x + (size_t)i * 4);
    ushort4 o;
    o.x = f2bf(v.x); o.y = f2bf(v.y); o.z = f2bf(v.z); o.w = f2bf(v.w);
    *(ushort4*)(xh + (size_t)i * 4) = o;
}

// W1 [128][256] fp32 -> W1t [256][128] bf16. Block n handles one output row.
__global__ __launch_bounds__(128) void k_prep_w(const float* __restrict__ W1,
        unsigned short* __restrict__ w1t) {
    int n = blockIdx.x;          // 0..255
    int k = threadIdx.x;         // 0..127
    w1t[n * 128 + k] = f2bf(W1[k * 256 + n]);
}

// Histogram + rank assignment: pos[e] = #earlier-processed edges with same dst.
__global__ void k_count(const int* __restrict__ edges, const int* __restrict__ flag,
                        int* __restrict__ cnt, int* __restrict__ pos, long long E) {
    long long e = (long long)blockIdx.x * blockDim.x + threadIdx.x;
    if (e >= E) return;
    int stride = flag[0];
    int d = edges[(E + e) * stride];
    pos[e] = atomicAdd(&cnt[d], 1);
}

// Per-block sums of cnt (8 elems/thread).
__global__ __launch_bounds__(256) void k_scan_partial(
        const int* __restrict__ cnt, int* __restrict__ bsum, int n) {
    int t = threadIdx.x;
    int idx = blockIdx.x * SCAN_TILE + t * 8;
    int s = 0;
#pragma unroll
    for (int j = 0; j < 8; ++j) {
        int i = idx + j;
        if (i < n) s += cnt[i];
    }
    for (int off = 32; off; off >>= 1) s += __shfl_down(s, off, 64);
    __shared__ int ws[4];
    if ((t & 63) == 0) ws[t >> 6] = s;
    __syncthreads();
    if (t == 0) bsum[blockIdx.x] = ws[0] + ws[1] + ws[2] + ws[3];
}

// Exclusive scan of <=64 block sums, in place, one wave.
__global__ void k_scan_tops(int* __restrict__ bsum, int nb) {
    int t = threadIdx.x;
    int w = (t < nb) ? bsum[t] : 0;
    int v = w;
    for (int off = 1; off < 64; off <<= 1) {
        int u = __shfl_up(v, off, 64);
        if (t >= off) v += u;
    }
    if (t < nb) bsum[t] = v - w;   // exclusive
}

// Apply: recompute intra-block prefix, add block offset, emit row_start & dis.
__global__ __launch_bounds__(256) void k_scan_apply(
        const int* __restrict__ cnt, const int* __restrict__ bsum,
        int* __restrict__ row_start, float* __restrict__ dis, int n) {
    int t = threadIdx.x;
    int lane = t & 63, w = t >> 6;
    int idx = blockIdx.x * SCAN_TILE + t * 8;
    int vals[8];
    int s = 0;
#pragma unroll
    for (int j = 0; j < 8; ++j) {
        int i = idx + j;
        vals[j] = (i < n) ? cnt[i] : 0;
        s += vals[j];
    }
    int inc = s;
    for (int off = 1; off < 64; off <<= 1) {
        int u = __shfl_up(inc, off, 64);
        if (lane >= off) inc += u;
    }
    __shared__ int wsum[4];
    if (lane == 63) wsum[w] = inc;
    __syncthreads();
    int woff = 0;
    for (int i = 0; i < w; ++i) woff += wsum[i];
    int ex = bsum[blockIdx.x] + woff + inc - s;  // exclusive prefix of this chunk
#pragma unroll
    for (int j = 0; j < 8; ++j) {
        int i = idx + j;
        if (i < n) {
            row_start[i] = ex;
            dis[i] = rsqrtf((float)vals[j] + 1.0f);  // +1 = self loop
            ex += vals[j];
        }
    }
    if (idx <= n && n < idx + 8) row_start[n] = ex;  // unique thread
}

// Pure scattered store: csr_src[rs[dst] + pos[e]] = src. No atomics.
__global__ void k_scatter(const int* __restrict__ edges, const int* __restrict__ flag,
                          const int* __restrict__ row_start, const int* __restrict__ pos,
                          int* __restrict__ csr_src, long long E) {
    long long e = (long long)blockIdx.x * blockDim.x + threadIdx.x;
    if (e >= E) return;
    int stride = flag[0];
    int s = edges[e * stride];
    int d = edges[(E + e) * stride];
    csr_src[row_start[d] + pos[e]] = s;
}

// One wave per node; lane owns features {2*lane, 2*lane+1} (one uint = 2 bf16).
// fp32 accumulate, bf16 output.
__global__ __launch_bounds__(256) void k_agg(
        const unsigned short* __restrict__ xh, const int* __restrict__ csr_src,
        const int* __restrict__ row_start, const float* __restrict__ dis,
        unsigned short* __restrict__ aggh, int n) {
    int wid  = (blockIdx.x * blockDim.x + threadIdx.x) >> 6;
    int lane = threadIdx.x & 63;
    if (wid >= n) return;
    int start = row_start[wid], end = row_start[wid + 1];
    float dn = dis[wid];
    unsigned int self = ((const unsigned int*)(xh + (size_t)wid * 128))[lane];
    float acc0 = dn * dn * bf_lo(self);
    float acc1 = dn * dn * bf_hi(self);
    int e = start;
    for (; e + 3 < end; e += 4) {
        int s0 = csr_src[e],     s1 = csr_src[e + 1];
        int s2 = csr_src[e + 2], s3 = csr_src[e + 3];
        float n0 = dis[s0] * dn, n1 = dis[s1] * dn;
        float n2 = dis[s2] * dn, n3 = dis[s3] * dn;
        unsigned int v0 = ((const unsigned int*)(xh + (size_t)s0 * 128))[lane];
        unsigned int v1 = ((const unsigned int*)(xh + (size_t)s1 * 128))[lane];
        unsigned int v2 = ((const unsigned int*)(xh + (size_t)s2 * 128))[lane];
        unsigned int v3 = ((const unsigned int*)(xh + (size_t)s3 * 128))[lane];
        acc0 += n0 * bf_lo(v0); acc1 += n0 * bf_hi(v0);
        acc0 += n1 * bf_lo(v1); acc1 += n1 * bf_hi(v1);
        acc0 += n2 * bf_lo(v2); acc1 += n2 * bf_hi(v2);
        acc0 += n3 * bf_lo(v3); acc1 += n3 * bf_hi(v3);
    }
    for (; e < end; ++e) {
        int s0 = csr_src[e];
        float n0 = dis[s0] * dn;
        unsigned int v0 = ((const unsigned int*)(xh + (size_t)s0 * 128))[lane];
        acc0 += n0 * bf_lo(v0); acc1 += n0 * bf_hi(v0);
    }
    unsigned int pack = (unsigned int)f2bf(acc0) | ((unsigned int)f2bf(acc1) << 16);
    ((unsigned int*)(aggh + (size_t)wid * 128))[lane] = pack;
}

// MFMA GEMM: sv = relu(agg @ W1 + b1) @ W2.
// Wave = 16 nodes x 256 cols (16 col-tiles of 16x16x32 MFMA, K=128).
// A layout: A[m=lane&15][k=quad*8+j]; B: B[k=quad*8+j][n=lane&15];
// C/D: col=lane&15, row=quad*4+reg.
__global__ __launch_bounds__(256) void k_mm(
        const unsigned short* __restrict__ aggh, const unsigned short* __restrict__ w1t,
        const float* __restrict__ b1, const float* __restrict__ W2,
        float* __restrict__ sv, int n) {
    int wave = threadIdx.x >> 6;        // 0..3
    int lane = threadIdx.x & 63;
    int m    = lane & 15;
    int quad = lane >> 4;               // 0..3
    int node0 = blockIdx.x * 64 + wave * 16;

    bf16x8 afrag[4];
    const unsigned short* arow = aggh + (size_t)(node0 + m) * 128 + quad * 8;
#pragma unroll
    for (int ks = 0; ks < 4; ++ks)
        afrag[ks] = *(const bf16x8*)(arow + ks * 32);

    float p0 = 0.f, p1 = 0.f, p2 = 0.f, p3 = 0.f;
#pragma unroll 1
    for (int t = 0; t < 16; ++t) {
        const unsigned short* brow = w1t + (size_t)(t * 16 + m) * 128 + quad * 8;
        f32x4 acc = {0.f, 0.f, 0.f, 0.f};
#pragma unroll
        for (int ks = 0; ks < 4; ++ks) {
            bf16x8 bfrag = *(const bf16x8*)(brow + ks * 32);
            acc = __builtin_amdgcn_mfma_f32_16x16x32_bf16(afrag[ks], bfrag, acc, 0, 0, 0);
        }
        int col = t * 16 + m;
        float bb = b1[col], w2 = W2[col];
        float h0 = acc[0] + bb, h1 = acc[1] + bb, h2 = acc[2] + bb, h3 = acc[3] + bb;
        p0 += (h0 > 0.f ? h0 : 0.f) * w2;
        p1 += (h1 > 0.f ? h1 : 0.f) * w2;
        p2 += (h2 > 0.f ? h2 : 0.f) * w2;
        p3 += (h3 > 0.f ? h3 : 0.f) * w2;
    }
    // sum over the 16 cols: butterfly across lanes within each quad group
#pragma unroll
    for (int off = 1; off < 16; off <<= 1) {
        p0 += __shfl_xor(p0, off, 64);
        p1 += __shfl_xor(p1, off, 64);
        p2 += __shfl_xor(p2, off, 64);
        p3 += __shfl_xor(p3, off, 64);
    }
    if (m == 0) {
        int nb = node0 + quad * 4;
        if (nb + 0 < n) sv[nb + 0] = p0;
        if (nb + 1 < n) sv[nb + 1] = p1;
        if (nb + 2 < n) sv[nb + 2] = p2;
        if (nb + 3 < n) sv[nb + 3] = p3;
    }
}

// out[i] = b2 + dis_i * (dis_i * s[i] + sum_e dis[src] * s[src]); wave per node.
__global__ __launch_bounds__(256) void k_out(
        const float* __restrict__ sv, const int* __restrict__ csr_src,
        const int* __restrict__ row_start, const float* __restrict__ dis,
        const float* __restrict__ b2, float* __restrict__ out, int n) {
    int wid  = (blockIdx.x * blockDim.x + threadIdx.x) >> 6;
    int lane = threadIdx.x & 63;
    if (wid >= n) return;
    int start = row_start[wid], end = row_start[wid + 1];
    float dn = dis[wid];
    float acc = 0.f;
    for (int e = start + lane; e < end; e += 64) {
        int s = csr_src[e];
        acc += dis[s] * sv[s];
    }
    for (int off = 32; off; off >>= 1) acc += __shfl_down(acc, off, 64);
    if (lane == 0)
        out[wid] = dn * (acc + dn * sv[wid]) + b2[0];
}

extern "C" void kernel_launch(void* const* d_in, const int* in_sizes, int n_in,
                              void* d_out, int out_size, void* d_ws, size_t ws_size,
                              hipStream_t stream) {
    const float* x  = (const float*)d_in[0];
    const int*   ei = (const int*)d_in[1];
    const float* W1 = (const float*)d_in[2];
    const float* b1 = (const float*)d_in[3];
    const float* W2 = (const float*)d_in[4];
    const float* b2 = (const float*)d_in[5];
    float* out = (float*)d_out;

    const int N = in_sizes[0] / 128;
    const long long E = in_sizes[1] / 2;

    char* ws = (char*)d_ws;
    size_t off = 0;
    auto take = [&](size_t bytes) -> char* {
        char* p = ws + off;
        off = (off + bytes + 255) & ~(size_t)255;
        return p;
    };
    int*            flag    = (int*)take(4);
    int*            cnt     = (int*)take((size_t)N * 4);
    int*            rs      = (int*)take((size_t)(N + 1) * 4);
    float*          dis     = (float*)take((size_t)N * 4);
    float*          sv      = (float*)take((size_t)N * 4);
    int*            bsum    = (int*)take(64 * 4);
    int*            pos     = (int*)take((size_t)E * 4);
    int*            csr_src = (int*)take((size_t)E * 4);
    unsigned short* xh      = (unsigned short*)take((size_t)N * 128 * 2);
    unsigned short* w1t     = (unsigned short*)take((size_t)256 * 128 * 2);
    unsigned short* aggh    = (unsigned short*)take((size_t)(N + 64) * 128 * 2); // pad for mm tail

    int nb_n  = (N + 255) / 256;
    int nb_e  = (int)((E + 255) / 256);
    int nb_s  = (N + SCAN_TILE - 1) / SCAN_TILE;   // 25 for N=50000
    int nb_x  = (N * 128 / 4 + 255) / 256;
    int nb_mm = (N + 63) / 64;

    k_init        <<<nb_n, 256, 0, stream>>>(ei, flag, cnt, N);
    k_prep_x      <<<nb_x, 256, 0, stream>>>(x, xh, N * 128 / 4);
    k_prep_w      <<<256, 128, 0, stream>>>(W1, w1t);
    k_count       <<<nb_e, 256, 0, stream>>>(ei, flag, cnt, pos, E);
    k_scan_partial<<<nb_s, 256, 0, stream>>>(cnt, bsum, N);
    k_scan_tops   <<<1, 64, 0, stream>>>(bsum, nb_s);
    k_scan_apply  <<<nb_s, 256, 0, stream>>>(cnt, bsum, rs, dis, N);
    k_scatter     <<<nb_e, 256, 0, stream>>>(ei, flag, rs, pos, csr_src, E);
    k_agg         <<<(N + 3) / 4, 256, 0, stream>>>(xh, csr_src, rs, dis, aggh, N);
    k_mm          <<<nb_mm, 256, 0, stream>>>(aggh, w1t, b1, W2, sv, N);
    k_out         <<<(N + 3) / 4, 256, 0, stream>>>(sv, csr_src, rs, dis, b2, out, N);
}